// Round 4
// baseline (206.681 us; speedup 1.0000x reference)
//
#include <hip/hip_runtime.h>

// Problem constants (T=512, B=16 -> 8192 tokens), all tensors float32
#define NTOK 8192
#define CDIM 512
#define NB   8
#define RD   64
#define OD   512

// Phase A geometry: 512 blocks x 128 threads (2 waves), 16 tokens/block,
// 8 tokens per wave.
#define TPB_A 16
#define XPAD  4                    // pad x rows to 516 f32: float4-aligned
#define XROW  (CDIM + XPAD)        // 516
#define XROW4 (XROW / 4)           // 129
#define SL    8                    // float4-columns of w1 per LDS slice
#define NSL   (CDIM / 4 / SL)      // 16 slices

typedef unsigned char u8;

__device__ __forceinline__ float4 f4add(float4 a, float4 b) {
    return make_float4(a.x + b.x, a.y + b.y, a.z + b.z, a.w + b.w);
}
// Exact expression shape of the verified kernel: ((wx*xx + wy*xy) + wz*xz) + ww*xw
__device__ __forceinline__ float dot4(float4 a, float4 b) {
    return a.x * b.x + a.y * b.y + a.z * b.z + a.w * b.w;
}

// ---------------------------------------------------------------------------
// Phase A. Round-3 post-mortem: per-lane w1-row reads (64 lanes x 2KB stride)
// make every VMEM instruction a 64-cache-line gather -> VMEM request-rate
// wall (~32K line-req/CU), invariant under prefetch depth and occupancy.
// Fix: stage w1 through LDS in 16 column-slices, transposed to [c4][row] so
// the v-loop LDS read is lane-consecutive (bank-floor). Global staging reads
// are 8-consecutive-float4 runs (16 lines/instr, 4x fewer requests). Slice
// s+1 is register-prefetched (4 named float4) during compute of slice s;
// one barrier per slice (double-buffered). v summation order is bitwise-
// identical to the verified kernels (j-ascending dot4 per acc chain).
// ---------------------------------------------------------------------------
__global__ __launch_bounds__(128, 2) void phaseA(
    const float* __restrict__ x, const float* __restrict__ map_w,
    const float* __restrict__ map_b, const float* __restrict__ w1,
    u8* __restrict__ q_out, float* __restrict__ v_out,
    float* __restrict__ loss_out)
{
    const int t    = threadIdx.x;
    const int tok0 = blockIdx.x * TPB_A;
    __shared__ __align__(16) float  xs[TPB_A * XROW];   // 33,024 B
    __shared__ __align__(16) float4 wsl[2][SL * RD];    // 16,384 B

    // ---- stage x tile (16 independent float4 loads/thread, coalesced) ----
    const float4* xsrc = (const float4*)(x + (size_t)tok0 * CDIM);
    #pragma unroll
    for (int i = t; i < TPB_A * (CDIM / 4); i += 128) {
        int r = i >> 7, c = i & 127;                    // CDIM/4 = 128
        *((float4*)(xs + r * XROW) + c) = xsrc[i];
    }

    // ---- w1 slice addressing: thread owns 4 float4 per slice ----
    // element k: i = k*128 + t -> local row rK = i>>3 (0..63), col cK = i&7
    const float4* w1g = (const float4*)w1;              // [64][128] float4
    const int i1 = 128 + t, i2 = 256 + t, i3 = 384 + t;
    const int r0 = t  >> 3, c0 = t  & 7;
    const int r1 = i1 >> 3, c1 = i1 & 7;
    const int r2 = i2 >> 3, c2 = i2 & 7;
    const int r3 = i3 >> 3, c3 = i3 & 7;
    // prefetch slice 0 (in flight across logits)
    float4 A0 = w1g[r0 * 128 + c0];
    float4 A1 = w1g[r1 * 128 + c1];
    float4 A2 = w1g[r2 * 128 + c2];
    float4 A3 = w1g[r3 * 128 + c3];

    __syncthreads();

    // ---- logits: one thread per (token,bit), full-C f64 accumulation ----
    // (verbatim from the verified round-3 kernel; map_w is 16 KB = L1-hot)
    {
        const int bit = t & 7, tk = t >> 3;             // tk in 0..15
        const float4* m4 = (const float4*)(map_w + (size_t)bit * CDIM);
        const float4* x4 = (const float4*)xs + tk * XROW4;
        double a0 = 0.0, a1 = 0.0;
        for (int j = 0; j < CDIM / 4; ++j) {
            float4 m = m4[j], xv = x4[j];
            a0 += (double)m.x * (double)xv.x + (double)m.y * (double)xv.y;
            a1 += (double)m.z * (double)xv.z + (double)m.w * (double)xv.w;
        }
        double k = a0 + a1 + (double)map_b[bit];
        unsigned long long m = __ballot(k > 0.0);
        const int lane = t & 63;
        if ((lane & 7) == 0) {
            int g = lane >> 3;                          // local token in wave
            q_out[tok0 + tk] = (u8)((m >> (g * 8)) & 0xFFull);
        }
    }

    // ---- v: wave tg -> tokens tg*8..tg*8+7, lane r = w1 row ----
    {
        const int r  = t & 63;
        const int tg = t >> 6;                          // 0..1
        const float4* xq4 = (const float4*)xs + (size_t)(tg * 8) * XROW4;
        float acc0 = 0.f, acc1 = 0.f, acc2 = 0.f, acc3 = 0.f;
        float acc4 = 0.f, acc5 = 0.f, acc6 = 0.f, acc7 = 0.f;
        float4 B0, B1, B2, B3;

        for (int s = 0; s < NSL; ++s) {
            // publish slice s (writes land in the buffer not being read)
            float4* wb = &wsl[s & 1][0];
            wb[c0 * RD + r0] = A0;
            wb[c1 * RD + r1] = A1;
            wb[c2 * RD + r2] = A2;
            wb[c3 * RD + r3] = A3;
            // prefetch slice s+1 (covered by this slice's compute)
            if (s + 1 < NSL) {
                const int off = (s + 1) * SL;
                B0 = w1g[r0 * 128 + off + c0];
                B1 = w1g[r1 * 128 + off + c1];
                B2 = w1g[r2 * 128 + off + c2];
                B3 = w1g[r3 * 128 + off + c3];
            }
            __syncthreads();
            #pragma unroll
            for (int i4 = 0; i4 < SL; ++i4) {
                float4 wv = wb[i4 * RD + r];            // lane-consecutive LDS
                const int jg = s * SL + i4;             // global j4, ascending
                acc0 += dot4(wv, xq4[jg]);
                acc1 += dot4(wv, xq4[1 * XROW4 + jg]);
                acc2 += dot4(wv, xq4[2 * XROW4 + jg]);
                acc3 += dot4(wv, xq4[3 * XROW4 + jg]);
                acc4 += dot4(wv, xq4[4 * XROW4 + jg]);
                acc5 += dot4(wv, xq4[5 * XROW4 + jg]);
                acc6 += dot4(wv, xq4[6 * XROW4 + jg]);
                acc7 += dot4(wv, xq4[7 * XROW4 + jg]);
            }
            A0 = B0; A1 = B1; A2 = B2; A3 = B3;
        }

        float* vo = v_out + (size_t)(tok0 + tg * 8) * RD + r;   // coalesced
        vo[0 * RD] = acc0; vo[1 * RD] = acc1; vo[2 * RD] = acc2; vo[3 * RD] = acc3;
        vo[4 * RD] = acc4; vo[5 * RD] = acc5; vo[6 * RD] = acc6; vo[7 * RD] = acc7;
    }

    if (blockIdx.x == 0 && t == 0) loss_out[0] = 0.0f;  // loss = 0
}

// ---------------------------------------------------------------------------
// Phase B. Round-3 post-mortem: per-thread weight rows (64 lanes x 256B
// stride) were a 64-line gather per instruction -> ~47 us in every round.
// Fix: read the block's 2x32KB weight chunk COALESCED (lane-stride-1, 32
// named float4/thread, issued before the scan so they fly across it), sum,
// store to LDS with a +row mod-16 swizzle (bank-floor both sides), then read
// back each thread's fused row into 16 named registers. Inner loop verbatim.
// ---------------------------------------------------------------------------
__global__ __launch_bounds__(128, 2) void phaseB(
    const u8* __restrict__ q_arr, const float* __restrict__ v_arr,
    const float* __restrict__ w21, const float* __restrict__ w22,
    const float* __restrict__ pwB, float* __restrict__ y)
{
    const int q  = blockIdx.x >> 2;
    const int qu = blockIdx.x & 3;
    const int t  = threadIdx.x;
    const int o  = qu * 128 + t;

    __shared__ unsigned short list[NTOK];        // 16 KB
    __shared__ int cnt;
    __shared__ __align__(16) float4 wsum[128 * 16];  // 32 KB fused chunk
    __shared__ __align__(16) float vs[8 * RD];   // 2 KB

    // ---- 1. q_arr into registers FIRST (retires before the weight burst) ----
    const uint4* qa = (const uint4*)q_arr;
    uint4 qv0 = qa[t], qv1 = qa[t + 128], qv2 = qa[t + 256], qv3 = qa[t + 384];

    // ---- 2. coalesced weight-chunk loads (32 named float4, lane-stride-1) ----
    const float4* b21 = (const float4*)w21 + (size_t)q * (OD * RD / 4) + (size_t)qu * 2048;
    const float4* b22 = (const float4*)w22 + (size_t)(255 - q) * (OD * RD / 4) + (size_t)qu * 2048;
    float4 s0 = b21[t],        s1 = b21[t + 128],  s2 = b21[t + 256],  s3 = b21[t + 384],
           s4 = b21[t + 512],  s5 = b21[t + 640],  s6 = b21[t + 768],  s7 = b21[t + 896],
           s8 = b21[t + 1024], s9 = b21[t + 1152], s10 = b21[t + 1280], s11 = b21[t + 1408],
           s12 = b21[t + 1536], s13 = b21[t + 1664], s14 = b21[t + 1792], s15 = b21[t + 1920];
    float4 u0 = b22[t],        u1 = b22[t + 128],  u2 = b22[t + 256],  u3 = b22[t + 384],
           u4 = b22[t + 512],  u5 = b22[t + 640],  u6 = b22[t + 768],  u7 = b22[t + 896],
           u8 = b22[t + 1024], u9 = b22[t + 1152], u10 = b22[t + 1280], u11 = b22[t + 1408],
           u12 = b22[t + 1536], u13 = b22[t + 1664], u14 = b22[t + 1792], u15 = b22[t + 1920];

    if (t == 0) cnt = 0;
    __syncthreads();

    // ---- 3. scan from registers, LDS atomic append (verbatim) ----
#define CHK(WORD, SB, OFF) { unsigned uw = (WORD); \
    if ((int)(uw & 0xFFu)         == q) list[atomicAdd(&cnt, 1)] = (unsigned short)((SB) + (OFF));     \
    if ((int)((uw >> 8)  & 0xFFu) == q) list[atomicAdd(&cnt, 1)] = (unsigned short)((SB) + (OFF) + 1); \
    if ((int)((uw >> 16) & 0xFFu) == q) list[atomicAdd(&cnt, 1)] = (unsigned short)((SB) + (OFF) + 2); \
    if ((int)(uw >> 24)           == q) list[atomicAdd(&cnt, 1)] = (unsigned short)((SB) + (OFF) + 3); }
    { int sb = t * 16;          CHK(qv0.x, sb, 0) CHK(qv0.y, sb, 4) CHK(qv0.z, sb, 8) CHK(qv0.w, sb, 12) }
    { int sb = (t + 128) * 16;  CHK(qv1.x, sb, 0) CHK(qv1.y, sb, 4) CHK(qv1.z, sb, 8) CHK(qv1.w, sb, 12) }
    { int sb = (t + 256) * 16;  CHK(qv2.x, sb, 0) CHK(qv2.y, sb, 4) CHK(qv2.z, sb, 8) CHK(qv2.w, sb, 12) }
    { int sb = (t + 384) * 16;  CHK(qv3.x, sb, 0) CHK(qv3.y, sb, 4) CHK(qv3.z, sb, 8) CHK(qv3.w, sb, 12) }
#undef CHK

    // ---- 4. fuse (w21+w22) and store to LDS, +row mod-16 swizzle ----
#define PUT(K, SV, UV) { const int i = (K) * 128 + t; \
    const int slot = (i & ~15) | (((i & 15) + (i >> 4)) & 15); \
    wsum[slot] = f4add(SV, UV); }
    PUT(0, s0, u0)   PUT(1, s1, u1)   PUT(2, s2, u2)   PUT(3, s3, u3)
    PUT(4, s4, u4)   PUT(5, s5, u5)   PUT(6, s6, u6)   PUT(7, s7, u7)
    PUT(8, s8, u8)   PUT(9, s9, u9)   PUT(10, s10, u10) PUT(11, s11, u11)
    PUT(12, s12, u12) PUT(13, s13, u13) PUT(14, s14, u14) PUT(15, s15, u15)
#undef PUT
    __syncthreads();                                    // covers list + wsum
    const int n = cnt;
    if (n == 0) return;                                 // uniform exit

    // ---- 5. own fused row from LDS (swizzled, bank-floor) ----
    const int ss = t * 16;
    float4 w0 = wsum[ss + ((0 + t) & 15)],  w1 = wsum[ss + ((1 + t) & 15)],
           w2 = wsum[ss + ((2 + t) & 15)],  w3 = wsum[ss + ((3 + t) & 15)],
           w4 = wsum[ss + ((4 + t) & 15)],  w5 = wsum[ss + ((5 + t) & 15)],
           w6 = wsum[ss + ((6 + t) & 15)],  w7 = wsum[ss + ((7 + t) & 15)],
           w8 = wsum[ss + ((8 + t) & 15)],  w9 = wsum[ss + ((9 + t) & 15)],
           w10 = wsum[ss + ((10 + t) & 15)], w11 = wsum[ss + ((11 + t) & 15)],
           w12 = wsum[ss + ((12 + t) & 15)], w13 = wsum[ss + ((13 + t) & 15)],
           w14 = wsum[ss + ((14 + t) & 15)], w15 = wsum[ss + ((15 + t) & 15)];
    const float bias = pwB[o];

    // ---- 6. stream tokens in batches of 8, token pairs (verbatim) ----
    const float4* v4 = (const float4*)v_arr;
    for (int base = 0; base < n; base += 8) {
        const int nb = min(8, n - base);
        if (t < nb * 16)                                // 8 tok x 16 float4
            ((float4*)vs)[t] = v4[(size_t)list[base + (t >> 4)] * (RD / 4) + (t & 15)];
        __syncthreads();
        int i = 0;
        for (; i + 2 <= nb; i += 2) {
            const float4* p0 = (const float4*)vs + (size_t)i * 16;
            const float4* p1 = p0 + 16;
            float acc0 = bias, acc1 = bias;
#define STEP(J, W) { float4 x0 = p0[J], x1 = p1[J]; \
            acc0 += W.x * x0.x + W.y * x0.y + W.z * x0.z + W.w * x0.w; \
            acc1 += W.x * x1.x + W.y * x1.y + W.z * x1.z + W.w * x1.w; }
            STEP(0, w0)  STEP(1, w1)  STEP(2, w2)  STEP(3, w3)
            STEP(4, w4)  STEP(5, w5)  STEP(6, w6)  STEP(7, w7)
            STEP(8, w8)  STEP(9, w9)  STEP(10, w10) STEP(11, w11)
            STEP(12, w12) STEP(13, w13) STEP(14, w14) STEP(15, w15)
#undef STEP
            y[(size_t)list[base + i]     * OD + o] = acc0;
            y[(size_t)list[base + i + 1] * OD + o] = acc1;
        }
        if (i < nb) {                                   // odd tail
            const float4* p0 = (const float4*)vs + (size_t)i * 16;
            float acc0 = bias;
#define STEP1(J, W) { float4 x0 = p0[J]; \
            acc0 += W.x * x0.x + W.y * x0.y + W.z * x0.z + W.w * x0.w; }
            STEP1(0, w0)  STEP1(1, w1)  STEP1(2, w2)  STEP1(3, w3)
            STEP1(4, w4)  STEP1(5, w5)  STEP1(6, w6)  STEP1(7, w7)
            STEP1(8, w8)  STEP1(9, w9)  STEP1(10, w10) STEP1(11, w11)
            STEP1(12, w12) STEP1(13, w13) STEP1(14, w14) STEP1(15, w15)
#undef STEP1
            y[(size_t)list[base + i] * OD + o] = acc0;
        }
        __syncthreads();
    }
}

// ---------------------------------------------------------------------------
// Fallback (ws too small): workspace-free, one block per token.
// ---------------------------------------------------------------------------
__global__ __launch_bounds__(256) void mono(
    const float* __restrict__ x, const float* __restrict__ map_w,
    const float* __restrict__ map_b, const float* __restrict__ w1,
    const float* __restrict__ w21, const float* __restrict__ w22,
    const float* __restrict__ pwB, float* __restrict__ y)
{
    const int tok = blockIdx.x;
    const int t   = threadIdx.x;
    __shared__ float xsh[CDIM];
    __shared__ float vsh[RD];
    __shared__ int qsh;

    if (t == 0) qsh = 0;
    for (int i = t; i < CDIM; i += 256) xsh[i] = x[(size_t)tok * CDIM + i];
    __syncthreads();

    if (t < NB) {
        double a = 0.0;
        const float* mrow = map_w + (size_t)t * CDIM;
        for (int j = 0; j < CDIM; ++j) a += (double)mrow[j] * (double)xsh[j];
        a += (double)map_b[t];
        if (a > 0.0) atomicOr(&qsh, 1 << t);
    }
    if (t < RD) {
        const float* wrow = w1 + (size_t)t * CDIM;
        float acc = 0.f;
        for (int j = 0; j < CDIM; ++j) acc += wrow[j] * xsh[j];
        vsh[t] = acc;
    }
    __syncthreads();

    const int q = qsh;
    for (int o = t; o < OD; o += 256) {
        const float* pa = w21 + (size_t)q * (OD * RD) + (size_t)o * RD;
        const float* pb = w22 + (size_t)(255 - q) * (OD * RD) + (size_t)o * RD;
        float acc = pwB[o];
        for (int r = 0; r < RD; ++r) acc += (pa[r] + pb[r]) * vsh[r];
        y[(size_t)tok * OD + o] = acc;
    }
    if (tok == 0 && t == 0) y[(size_t)NTOK * OD] = 0.0f;
}

extern "C" void kernel_launch(void* const* d_in, const int* in_sizes, int n_in,
                              void* d_out, int out_size, void* d_ws, size_t ws_size,
                              hipStream_t stream) {
    const float* x     = (const float*)d_in[0];
    // d_in[1] = key: unused by the forward pass
    const float* map_w = (const float*)d_in[2];
    const float* map_b = (const float*)d_in[3];
    const float* w1    = (const float*)d_in[4];
    const float* w21   = (const float*)d_in[5];
    const float* w22   = (const float*)d_in[6];
    const float* pwB   = (const float*)d_in[7];
    float* out = (float*)d_out;

    const size_t need = (size_t)NTOK + (size_t)NTOK * RD * sizeof(float); // 8KB + 2MB
    if (ws_size >= need) {
        u8*    q_ws = (u8*)d_ws;
        float* v_ws = (float*)((char*)d_ws + NTOK);
        phaseA<<<NTOK / TPB_A, 128, 0, stream>>>(x, map_w, map_b, w1, q_ws, v_ws,
                                                 out + (size_t)NTOK * OD);
        phaseB<<<256 * 4, 128, 0, stream>>>(q_ws, v_ws, w21, w22, pwB, out);
    } else {
        mono<<<NTOK, 256, 0, stream>>>(x, map_w, map_b, w1, w21, w22, pwB, out);
    }
}